// Round 2
// baseline (304.463 us; speedup 1.0000x reference)
//
#include <hip/hip_runtime.h>
#include <hip/hip_bf16.h>

typedef unsigned short u16;
typedef unsigned int u32;
typedef __attribute__((ext_vector_type(8))) __bf16 bf16x8;
typedef __attribute__((ext_vector_type(4))) float f32x4;
typedef __attribute__((ext_vector_type(4))) u32 u32x4;

#define DEVFN static __device__ __forceinline__

DEVFN float bf2f(u16 v) { union { u32 u; float f; } x; x.u = (u32)v << 16; return x.f; }
DEVFN u16 f2bf(float f) {
    union { float f; u32 u; } x; x.f = f;
    u32 r = x.u + 0x7fff + ((x.u >> 16) & 1);
    return (u16)(r >> 16);
}

DEVFN void gload_lds16(const u16* g, u16* l) {
    __builtin_amdgcn_global_load_lds((const __attribute__((address_space(1))) u32*)g,
                                     (__attribute__((address_space(3))) u32*)l, 16, 0, 0);
}

// ---------------------------------------------------------------------------
// Generic C = A (M,K) @ B^T (N,K), bf16 in, f32 accum.
// OUTMODE: 0 = bf16 C; 1 = f32 C (+opt f32 bias/residual); 2 = bf16 Vt store
// Tile 128 x BN, BK=32, 256 threads = 4 waves in 2x2, wave tile 64 x BN/2.
// LDS layout is row-major [rows][32] per tile == fragment-linear for the
// 16x16x32 A/B mapping (lane l reads row l&15, k-chunk l>>4), so both the
// global_load_lds staging (linear lane x 16B) and ds_read_b128 fragment
// reads are conflict-free by construction.
// Batched via blockIdx.z: z = zb*8 + zh with independent strides (b, h).
// ---------------------------------------------------------------------------
template<int BN, int OUTMODE, bool BIAS, bool RES>
__global__ __launch_bounds__(256)
void gemm_bt(const u16* __restrict__ A, const u16* __restrict__ B,
             void* __restrict__ Cv, const float* __restrict__ bias,
             const float* __restrict__ res,
             int K, int lda, int ldb, int ldc,
             long sAb, long sAh, long sBb, long sBh, long sCb, long sCh,
             float scale)
{
    constexpr int NF = BN / 32;  // n-frags per wave
    __shared__ u16 smem[4096 + BN * 32];
    const int tid = threadIdx.x;
    const int lane = tid & 63, wave = tid >> 6;
    const int wr = wave >> 1, wc = wave & 1;
    const int z = blockIdx.z, zb = z >> 3, zh = z & 7;

    const u16* Ab = A + zb * sAb + zh * sAh + (long)blockIdx.x * 128 * lda;
    const u16* Bb = B + zb * sBb + zh * sBh + (long)blockIdx.y * BN * ldb;

    const int ra = tid >> 2, ca = (tid & 3) * 8;
    const u16* pA0 = Ab + (long)ra * lda + ca;
    const u16* pA1 = Ab + (long)(ra + 64) * lda + ca;
    u16* lA0 = smem + tid * 8;
    u16* lA1 = smem + (256 + tid) * 8;
    const u16* pB0 = Bb + (long)ra * ldb + ca;
    const u16* pB1 = Bb + (long)(ra + 64) * ldb + ca;
    u16* lB0 = smem + 4096 + tid * 8;
    u16* lB1 = smem + 4096 + (256 + tid) * 8;

    const int foff = ((lane & 15) * 4 + (lane >> 4)) * 8;  // frag offset (u16)
    const u16* aF = smem + wr * 2048 + foff;
    const u16* bF = smem + 4096 + wc * (NF * 512) + foff;

    f32x4 acc[4][NF];
#pragma unroll
    for (int i = 0; i < 4; ++i)
#pragma unroll
        for (int j = 0; j < NF; ++j) acc[i][j] = (f32x4){0.f, 0.f, 0.f, 0.f};

    for (int k0 = 0; k0 < K; k0 += 32) {
        gload_lds16(pA0 + k0, lA0);
        gload_lds16(pA1 + k0, lA1);
        gload_lds16(pB0 + k0, lB0);
        if constexpr (BN == 128) gload_lds16(pB1 + k0, lB1);
        asm volatile("s_waitcnt vmcnt(0)" ::: "memory");
        __syncthreads();
        bf16x8 av[4], bv[NF];
#pragma unroll
        for (int i = 0; i < 4; ++i) av[i] = *(const bf16x8*)(aF + i * 512);
#pragma unroll
        for (int j = 0; j < NF; ++j) bv[j] = *(const bf16x8*)(bF + j * 512);
#pragma unroll
        for (int i = 0; i < 4; ++i)
#pragma unroll
            for (int j = 0; j < NF; ++j)
                acc[i][j] = __builtin_amdgcn_mfma_f32_16x16x32_bf16(av[i], bv[j], acc[i][j], 0, 0, 0);
        __syncthreads();
    }

    const int m0 = blockIdx.x * 128 + wr * 64 + (lane >> 4) * 4;
    const int n0 = blockIdx.y * BN + wc * (BN / 2) + (lane & 15);
    if constexpr (OUTMODE == 0) {
        u16* Cb = (u16*)Cv + zb * sCb + zh * sCh;
#pragma unroll
        for (int i = 0; i < 4; ++i)
#pragma unroll
            for (int j = 0; j < NF; ++j) {
                int n = n0 + j * 16;
#pragma unroll
                for (int r = 0; r < 4; ++r) {
                    int m = m0 + i * 16 + r;
                    Cb[(long)m * ldc + n] = f2bf(acc[i][j][r] * scale);
                }
            }
    } else if constexpr (OUTMODE == 1) {
        float* Cb = (float*)Cv + zb * sCb + zh * sCh;
#pragma unroll
        for (int i = 0; i < 4; ++i)
#pragma unroll
            for (int j = 0; j < NF; ++j) {
                int n = n0 + j * 16;
                float bv_ = BIAS ? bias[n] : 0.f;
#pragma unroll
                for (int r = 0; r < 4; ++r) {
                    int m = m0 + i * 16 + r;
                    float v = acc[i][j][r] * scale + bv_;
                    if constexpr (RES) v += res[(long)m * ldc + n];
                    Cb[(long)m * ldc + n] = v;
                }
            }
    } else {
        // store V transposed: Vt[(b*8+h)][d][s]; m=b*256+s, n=h*64+d
#pragma unroll
        for (int i = 0; i < 4; ++i) {
            int m = m0 + i * 16;
            int b = m >> 8, s = m & 255;
#pragma unroll
            for (int j = 0; j < NF; ++j) {
                int n = n0 + j * 16;
                int h = n >> 6, d = n & 63;
                ushort4 pk;
                pk.x = f2bf(acc[i][j][0]); pk.y = f2bf(acc[i][j][1]);
                pk.z = f2bf(acc[i][j][2]); pk.w = f2bf(acc[i][j][3]);
                *(ushort4*)((u16*)Cv + (((long)(b * 8 + h) * 64 + d) * 256 + s)) = pk;
            }
        }
    }
}

// ---------------------------------------------------------------------------
// GroupNorm stats: one block per (b,g); 4096x16 f32 reduction -> per-chan a,d
// ---------------------------------------------------------------------------
__global__ __launch_bounds__(256)
void gn_stats(const float* __restrict__ x, const float* __restrict__ gscale,
              const float* __restrict__ gbias, float* __restrict__ coefA,
              float* __restrict__ coefD)
{
    const int b = blockIdx.x >> 5, g = blockIdx.x & 31;
    const float* base = x + (long)b * 4096 * 512 + g * 16;
    const int tid = threadIdx.x;
    const int p0 = tid >> 2, c0 = (tid & 3) * 4;
    const float* tp = base + (long)p0 * 512 + c0;
    float sum = 0.f, sq = 0.f;
    for (int it = 0; it < 64; ++it) {
        float4 v = *(const float4*)(tp + (long)it * 64 * 512);
        sum += v.x + v.y + v.z + v.w;
        sq += v.x * v.x + v.y * v.y + v.z * v.z + v.w * v.w;
    }
#pragma unroll
    for (int off = 32; off; off >>= 1) {
        sum += __shfl_down(sum, off);
        sq  += __shfl_down(sq, off);
    }
    __shared__ float ssum[4], ssq[4];
    if ((tid & 63) == 0) { ssum[tid >> 6] = sum; ssq[tid >> 6] = sq; }
    __syncthreads();
    if (tid < 16) {
        float S = ssum[0] + ssum[1] + ssum[2] + ssum[3];
        float Q = ssq[0] + ssq[1] + ssq[2] + ssq[3];
        float mean = S * (1.f / 65536.f);
        float var = Q * (1.f / 65536.f) - mean * mean;
        float rstd = rsqrtf(var + 1e-5f);
        int c = g * 16 + tid;
        float a = gscale[c] * rstd;
        coefA[b * 512 + c] = a;
        coefD[b * 512 + c] = gbias[c] - mean * a;
    }
}

// apply GN affine, f32 -> bf16
__global__ __launch_bounds__(256)
void gn_apply(const float* __restrict__ x, const float* __restrict__ coefA,
              const float* __restrict__ coefD, u16* __restrict__ xn)
{
    long e = ((long)blockIdx.x * 256 + threadIdx.x) * 8;
    int b = (int)(e >> 21);
    int c = (int)(e & 511);
    float4 v0 = *(const float4*)(x + e);
    float4 v1 = *(const float4*)(x + e + 4);
    const float* pa = coefA + b * 512 + c;
    const float* pd = coefD + b * 512 + c;
    float f[8] = { v0.x, v0.y, v0.z, v0.w, v1.x, v1.y, v1.z, v1.w };
    u32x4 o;
#pragma unroll
    for (int q = 0; q < 4; ++q) {
        float g0 = f[q * 2] * pa[q * 2] + pd[q * 2];
        float g1 = f[q * 2 + 1] * pa[q * 2 + 1] + pd[q * 2 + 1];
        o[q] = (u32)f2bf(g0) | ((u32)f2bf(g1) << 16);
    }
    *(u32x4*)(xn + e) = o;
}

// f32 -> bf16 bulk convert (n multiple of 8*256)
__global__ __launch_bounds__(256)
void conv_bf16(const float* __restrict__ in, u16* __restrict__ out)
{
    long e = ((long)blockIdx.x * 256 + threadIdx.x) * 8;
    float4 v0 = *(const float4*)(in + e);
    float4 v1 = *(const float4*)(in + e + 4);
    float f[8] = { v0.x, v0.y, v0.z, v0.w, v1.x, v1.y, v1.z, v1.w };
    u32x4 o;
#pragma unroll
    for (int q = 0; q < 4; ++q)
        o[q] = (u32)f2bf(f[q * 2]) | ((u32)f2bf(f[q * 2 + 1]) << 16);
    *(u32x4*)(out + e) = o;
}

// 2D transpose f32 -> bf16 for weights (R,C multiples of 32)
__global__ __launch_bounds__(256)
void transpose_k(const float* __restrict__ in, u16* __restrict__ out, int R, int C)
{
    __shared__ u16 t[32][33];
    int tx = threadIdx.x & 31, ty = threadIdx.x >> 5;
    int r0 = blockIdx.y * 32, c0 = blockIdx.x * 32;
    for (int i = ty; i < 32; i += 8) t[i][tx] = f2bf(in[(long)(r0 + i) * C + c0 + tx]);
    __syncthreads();
    for (int i = ty; i < 32; i += 8) out[(long)(c0 + i) * R + r0 + tx] = t[tx][i];
}

// softmax over rows of 256 (in place, bf16). One wave per row.
__global__ __launch_bounds__(256)
void softmax_rows(u16* __restrict__ S)
{
    int row = blockIdx.x * 4 + (threadIdx.x >> 6);
    int lane = threadIdx.x & 63;
    u16* p = S + (long)row * 256 + lane * 4;
    ushort4 v = *(ushort4*)p;
    float f[4] = { bf2f(v.x), bf2f(v.y), bf2f(v.z), bf2f(v.w) };
    float m = fmaxf(fmaxf(f[0], f[1]), fmaxf(f[2], f[3]));
#pragma unroll
    for (int off = 32; off; off >>= 1) m = fmaxf(m, __shfl_xor(m, off));
    float s = 0.f;
#pragma unroll
    for (int i = 0; i < 4; ++i) { f[i] = __expf(f[i] - m); s += f[i]; }
#pragma unroll
    for (int off = 32; off; off >>= 1) s += __shfl_xor(s, off);
    float inv = 1.f / s;
    v.x = f2bf(f[0] * inv); v.y = f2bf(f[1] * inv);
    v.z = f2bf(f[2] * inv); v.w = f2bf(f[3] * inv);
    *(ushort4*)p = v;
}

extern "C" void kernel_launch(void* const* d_in, const int* in_sizes, int n_in,
                              void* d_out, int out_size, void* d_ws, size_t ws_size,
                              hipStream_t stream)
{
    const float* x    = (const float*)d_in[0];
    const float* cond = (const float*)d_in[1];
    const float* gsc  = (const float*)d_in[2];
    const float* gbi  = (const float*)d_in[3];
    const float* Wq   = (const float*)d_in[4];
    const float* Wk   = (const float*)d_in[5];
    const float* Wv   = (const float*)d_in[6];
    const float* Wo   = (const float*)d_in[7];
    const float* bo   = (const float*)d_in[8];

    char* ws = (char*)d_ws;
    size_t off = 0;
    auto alloc = [&](size_t bytes) -> void* {
        void* p = ws + off; off += (bytes + 255) & ~(size_t)255; return p;
    };
    u16* WqT   = (u16*)alloc(512 * 512 * 2);
    u16* WkT   = (u16*)alloc(512 * 768 * 2);
    u16* WvT   = (u16*)alloc(512 * 768 * 2);
    u16* WoT   = (u16*)alloc(512 * 512 * 2);
    float* cfA = (float*)alloc(8 * 512 * 4);
    float* cfD = (float*)alloc(8 * 512 * 4);
    u16* condb = (u16*)alloc(2048l * 768 * 2);
    u16* xn    = (u16*)alloc(33554432);   // also reused as attention output O
    u16* Qb    = (u16*)alloc(33554432);
    u16* Kb    = (u16*)alloc(2048l * 512 * 2);
    u16* Vt    = (u16*)alloc(2097152);
    const size_t scores_unit = 8l * 4096 * 256 * 2;  // per single batch
    int cb = 8;
    while (cb > 1 && off + (size_t)cb * scores_unit > ws_size) cb >>= 1;
    u16* Sc = (u16*)alloc((size_t)cb * scores_unit);
    u16* Ob = xn;

    transpose_k<<<dim3(16, 16), 256, 0, stream>>>(Wq, WqT, 512, 512);
    transpose_k<<<dim3(16, 24), 256, 0, stream>>>(Wk, WkT, 768, 512);
    transpose_k<<<dim3(16, 24), 256, 0, stream>>>(Wv, WvT, 768, 512);
    transpose_k<<<dim3(16, 16), 256, 0, stream>>>(Wo, WoT, 512, 512);
    conv_bf16<<<768, 256, 0, stream>>>(cond, condb);

    gn_stats<<<256, 256, 0, stream>>>(x, gsc, gbi, cfA, cfD);
    gn_apply<<<8192, 256, 0, stream>>>(x, cfA, cfD, xn);

    // Q = xn @ WqT        (32768 x 512 x 512)
    gemm_bt<128, 0, false, false><<<dim3(256, 4, 1), 256, 0, stream>>>(
        xn, WqT, Qb, nullptr, nullptr, 512, 512, 512, 512,
        0, 0, 0, 0, 0, 0, 1.f);
    // K = cond @ WkT      (2048 x 512 x 768)
    gemm_bt<128, 0, false, false><<<dim3(16, 4, 1), 256, 0, stream>>>(
        condb, WkT, Kb, nullptr, nullptr, 768, 768, 768, 512,
        0, 0, 0, 0, 0, 0, 1.f);
    // V = cond @ WvT, stored transposed per head -> Vt[b*8+h][64][256]
    gemm_bt<128, 2, false, false><<<dim3(16, 4, 1), 256, 0, stream>>>(
        condb, WvT, Vt, nullptr, nullptr, 768, 768, 768, 0,
        0, 0, 0, 0, 0, 0, 1.f);

    for (int b0 = 0; b0 < 8; b0 += cb) {
        // scores = (Qh @ Kh^T) / 8     per (b,h): 4096 x 256 x 64
        gemm_bt<128, 0, false, false><<<dim3(32, 2, cb * 8), 256, 0, stream>>>(
            Qb + (long)b0 * 4096 * 512, Kb + (long)b0 * 256 * 512, Sc,
            nullptr, nullptr, 64, 512, 512, 256,
            4096l * 512, 64, 256l * 512, 64, 8l * 4096 * 256, 4096l * 256, 0.125f);
        softmax_rows<<<cb * 8192, 256, 0, stream>>>(Sc);
        // O(head cols) = P @ Vt^T      per (b,h): 4096 x 64 x 256
        gemm_bt<64, 0, false, false><<<dim3(32, 1, cb * 8), 256, 0, stream>>>(
            Sc, Vt + (long)b0 * 8 * 64 * 256, Ob + (long)b0 * 4096 * 512,
            nullptr, nullptr, 256, 256, 256, 512,
            8l * 4096 * 256, 4096l * 256, 8l * 64 * 256, 64l * 256, 4096l * 512, 64, 1.f);
    }

    // out = x + O @ WoT + bo    (32768 x 512 x 512), f32 output
    gemm_bt<128, 1, true, true><<<dim3(256, 4, 1), 256, 0, stream>>>(
        Ob, WoT, d_out, bo, x, 512, 512, 512, 512,
        0, 0, 0, 0, 0, 0, 1.f);
}

// Round 3
// 231.623 us; speedup vs baseline: 1.3145x; 1.3145x over previous
//
#include <hip/hip_runtime.h>
#include <hip/hip_bf16.h>

typedef unsigned short u16;
typedef unsigned int u32;
typedef __attribute__((ext_vector_type(8))) __bf16 bf16x8;
typedef __attribute__((ext_vector_type(4))) float f32x4;
typedef __attribute__((ext_vector_type(16))) float f32x16;
typedef __attribute__((ext_vector_type(4))) u32 u32x4;

#define DEVFN static __device__ __forceinline__

DEVFN float bf2f(u16 v) { union { u32 u; float f; } x; x.u = (u32)v << 16; return x.f; }
DEVFN u16 f2bf(float f) {
    union { float f; u32 u; } x; x.f = f;
    u32 r = x.u + 0x7fff + ((x.u >> 16) & 1);
    return (u16)(r >> 16);
}
DEVFN u32 cvtpk(float lo, float hi) {
    return (u32)f2bf(lo) | ((u32)f2bf(hi) << 16);
}

DEVFN void gload_lds16(const u16* g, u16* l) {
    __builtin_amdgcn_global_load_lds((const __attribute__((address_space(1))) u32*)g,
                                     (__attribute__((address_space(3))) u32*)l, 16, 0, 0);
}

// ---------------------------------------------------------------------------
// Generic C = A (M,K) @ B^T (N,K), bf16 in, f32 accum.
// OUTMODE: 0 = bf16 C; 1 = f32 C (+opt f32 bias/residual); 2 = bf16 Vt store
// ---------------------------------------------------------------------------
template<int BN, int OUTMODE, bool BIAS, bool RES>
__global__ __launch_bounds__(256)
void gemm_bt(const u16* __restrict__ A, const u16* __restrict__ B,
             void* __restrict__ Cv, const float* __restrict__ bias,
             const float* __restrict__ res,
             int K, int lda, int ldb, int ldc,
             long sAb, long sAh, long sBb, long sBh, long sCb, long sCh,
             float scale)
{
    constexpr int NF = BN / 32;  // n-frags per wave
    __shared__ u16 smem[4096 + BN * 32];
    const int tid = threadIdx.x;
    const int lane = tid & 63, wave = tid >> 6;
    const int wr = wave >> 1, wc = wave & 1;
    const int z = blockIdx.z, zb = z >> 3, zh = z & 7;

    const u16* Ab = A + zb * sAb + zh * sAh + (long)blockIdx.x * 128 * lda;
    const u16* Bb = B + zb * sBb + zh * sBh + (long)blockIdx.y * BN * ldb;

    const int ra = tid >> 2, ca = (tid & 3) * 8;
    const u16* pA0 = Ab + (long)ra * lda + ca;
    const u16* pA1 = Ab + (long)(ra + 64) * lda + ca;
    u16* lA0 = smem + tid * 8;
    u16* lA1 = smem + (256 + tid) * 8;
    const u16* pB0 = Bb + (long)ra * ldb + ca;
    const u16* pB1 = Bb + (long)(ra + 64) * ldb + ca;
    u16* lB0 = smem + 4096 + tid * 8;
    u16* lB1 = smem + 4096 + (256 + tid) * 8;

    const int foff = ((lane & 15) * 4 + (lane >> 4)) * 8;  // frag offset (u16)
    const u16* aF = smem + wr * 2048 + foff;
    const u16* bF = smem + 4096 + wc * (NF * 512) + foff;

    f32x4 acc[4][NF];
#pragma unroll
    for (int i = 0; i < 4; ++i)
#pragma unroll
        for (int j = 0; j < NF; ++j) acc[i][j] = (f32x4){0.f, 0.f, 0.f, 0.f};

    for (int k0 = 0; k0 < K; k0 += 32) {
        gload_lds16(pA0 + k0, lA0);
        gload_lds16(pA1 + k0, lA1);
        gload_lds16(pB0 + k0, lB0);
        if constexpr (BN == 128) gload_lds16(pB1 + k0, lB1);
        asm volatile("s_waitcnt vmcnt(0)" ::: "memory");
        __syncthreads();
        bf16x8 av[4], bv[NF];
#pragma unroll
        for (int i = 0; i < 4; ++i) av[i] = *(const bf16x8*)(aF + i * 512);
#pragma unroll
        for (int j = 0; j < NF; ++j) bv[j] = *(const bf16x8*)(bF + j * 512);
#pragma unroll
        for (int i = 0; i < 4; ++i)
#pragma unroll
            for (int j = 0; j < NF; ++j)
                acc[i][j] = __builtin_amdgcn_mfma_f32_16x16x32_bf16(av[i], bv[j], acc[i][j], 0, 0, 0);
        __syncthreads();
    }

    const int m0 = blockIdx.x * 128 + wr * 64 + (lane >> 4) * 4;
    const int n0 = blockIdx.y * BN + wc * (BN / 2) + (lane & 15);
    if constexpr (OUTMODE == 0) {
        u16* Cb = (u16*)Cv + zb * sCb + zh * sCh;
#pragma unroll
        for (int i = 0; i < 4; ++i)
#pragma unroll
            for (int j = 0; j < NF; ++j) {
                int n = n0 + j * 16;
#pragma unroll
                for (int r = 0; r < 4; ++r) {
                    int m = m0 + i * 16 + r;
                    Cb[(long)m * ldc + n] = f2bf(acc[i][j][r] * scale);
                }
            }
    } else if constexpr (OUTMODE == 1) {
        float* Cb = (float*)Cv + zb * sCb + zh * sCh;
#pragma unroll
        for (int i = 0; i < 4; ++i)
#pragma unroll
            for (int j = 0; j < NF; ++j) {
                int n = n0 + j * 16;
                float bv_ = BIAS ? bias[n] : 0.f;
#pragma unroll
                for (int r = 0; r < 4; ++r) {
                    int m = m0 + i * 16 + r;
                    float v = acc[i][j][r] * scale + bv_;
                    if constexpr (RES) v += res[(long)m * ldc + n];
                    Cb[(long)m * ldc + n] = v;
                }
            }
    } else {
        // store V transposed: Vt[(b*8+h)][d][s]; m=b*256+s, n=h*64+d
#pragma unroll
        for (int i = 0; i < 4; ++i) {
            int m = m0 + i * 16;
            int b = m >> 8, s = m & 255;
#pragma unroll
            for (int j = 0; j < NF; ++j) {
                int n = n0 + j * 16;
                int h = n >> 6, d = n & 63;
                ushort4 pk;
                pk.x = f2bf(acc[i][j][0]); pk.y = f2bf(acc[i][j][1]);
                pk.z = f2bf(acc[i][j][2]); pk.w = f2bf(acc[i][j][3]);
                *(ushort4*)((u16*)Cv + (((long)(b * 8 + h) * 64 + d) * 256 + s)) = pk;
            }
        }
    }
}

// ---------------------------------------------------------------------------
// Fused attention: grid (32 qchunks, 64 bh), 256 threads = 4 waves.
// Per wave: 32 queries x all 256 keys, D=64. Swapped QK^T (S^T = K@Q) with
// mfma_32x32x16_bf16; softmax in-register (lane-local P-row); P -> PV B-frag
// via cvt_pk + half-swap (m214 recipe, shfl_xor variant); O^T accumulated,
// normalized, transposed through swizzled LDS, stored coalesced.
// Q must be pre-scaled by 1/8.
// ---------------------------------------------------------------------------
union U8 { u32 w[4]; bf16x8 v; };

__global__ __launch_bounds__(256)
void attn_fused(const u16* __restrict__ Q, const u16* __restrict__ K,
                const u16* __restrict__ Vt, u16* __restrict__ O)
{
    __shared__ u16 lds[32768];  // 64KB: K frags [0,32K), Vt frags [32K,64K)
    const int tid = threadIdx.x, lane = tid & 63, wave = tid >> 6;
    const int bh = blockIdx.y, b = bh >> 3, h = bh & 7;
    const int l31 = lane & 31, lh = lane >> 5;
    const long q0 = (long)b * 4096 + blockIdx.x * 128 + wave * 32;

    // ---- stage K frag-linear: frag f=stile*4+kc; entry(f,l):
    //   K[b*256 + stile*32 + (l&31)][h*64 + kc*16 + (l>>5)*8..+8]
    {
        const u16* Kb_ = K + (long)b * 256 * 512 + h * 64;
        const u16* Vb_ = Vt + (long)bh * 64 * 256;
#pragma unroll
        for (int r = 0; r < 8; ++r) {
            int f = r * 4 + wave;
            int stile = f >> 2, kc = f & 3;
            gload_lds16(Kb_ + (long)(stile * 32 + l31) * 512 + kc * 16 + lh * 8,
                        lds + f * 512 + lane * 8);
        }
        // Vt frags: f = dtile*16 + kstep; entry(f,l): Vt[bh][dtile*32+(l&31)][kstep*16+(l>>5)*8]
#pragma unroll
        for (int r = 0; r < 8; ++r) {
            int f = r * 4 + wave;
            int dtile = f >> 4, kstep = f & 15;
            gload_lds16(Vb_ + (long)(dtile * 32 + l31) * 256 + kstep * 16 + lh * 8,
                        lds + 16384 + f * 512 + lane * 8);
        }
    }
    // Q B-frags (col=q=lane&31, k=c): loaded once, direct global->reg
    bf16x8 qf[4];
    {
        const u16* Qp = Q + (q0 + l31) * 512 + h * 64 + lh * 8;
#pragma unroll
        for (int kc = 0; kc < 4; ++kc) qf[kc] = *(const bf16x8*)(Qp + kc * 16);
    }
    asm volatile("s_waitcnt vmcnt(0)" ::: "memory");
    __syncthreads();

    // ---- QK^T: S^T tiles, C layout col=q(lane&31), row=s_loc=(r&3)+8(r>>2)+4(lane>>5)
    f32x16 sc[8];
#pragma unroll
    for (int st = 0; st < 8; ++st)
#pragma unroll
        for (int r = 0; r < 16; ++r) sc[st][r] = 0.f;
#pragma unroll
    for (int st = 0; st < 8; ++st)
#pragma unroll
        for (int kc = 0; kc < 4; ++kc) {
            bf16x8 af = *(const bf16x8*)(lds + (st * 4 + kc) * 512 + lane * 8);
            sc[st] = __builtin_amdgcn_mfma_f32_32x32x16_bf16(af, qf[kc], sc[st], 0, 0, 0);
        }

    // ---- softmax over s (rows): in-lane over 128 regs + combine lane^32
    float m = -3e38f;
#pragma unroll
    for (int st = 0; st < 8; ++st)
#pragma unroll
        for (int r = 0; r < 16; ++r) m = fmaxf(m, sc[st][r]);
    m = fmaxf(m, __shfl_xor(m, 32));
    float sum = 0.f;
#pragma unroll
    for (int st = 0; st < 8; ++st)
#pragma unroll
        for (int r = 0; r < 16; ++r) {
            float e = __expf(sc[st][r] - m);
            sc[st][r] = e; sum += e;
        }
    sum += __shfl_xor(sum, 32);
    float inv = 1.f / sum;

    // ---- PV: O^T[d][q] += V^T-frag @ P-frag (unnormalized P)
    f32x16 oacc[2];
#pragma unroll
    for (int dt = 0; dt < 2; ++dt)
#pragma unroll
        for (int r = 0; r < 16; ++r) oacc[dt][r] = 0.f;
    const bool hiHalf = (lh != 0);
#pragma unroll
    for (int st = 0; st < 8; ++st) {
        u32 c0 = cvtpk(sc[st][0], sc[st][1]);
        u32 c1 = cvtpk(sc[st][2], sc[st][3]);
        u32 c2 = cvtpk(sc[st][4], sc[st][5]);
        u32 c3 = cvtpk(sc[st][6], sc[st][7]);
        u32 c4 = cvtpk(sc[st][8], sc[st][9]);
        u32 c5 = cvtpk(sc[st][10], sc[st][11]);
        u32 c6 = cvtpk(sc[st][12], sc[st][13]);
        u32 c7 = cvtpk(sc[st][14], sc[st][15]);
        // half-swap: {w0,w2} = swap(c0,c2) etc. (shfl_xor variant of permlane32_swap)
        u32 x0 = (u32)__shfl_xor((int)c0, 32), x2 = (u32)__shfl_xor((int)c2, 32);
        u32 x1 = (u32)__shfl_xor((int)c1, 32), x3 = (u32)__shfl_xor((int)c3, 32);
        u32 x4 = (u32)__shfl_xor((int)c4, 32), x6 = (u32)__shfl_xor((int)c6, 32);
        u32 x5 = (u32)__shfl_xor((int)c5, 32), x7 = (u32)__shfl_xor((int)c7, 32);
        U8 p0, p1;
        p0.w[0] = hiHalf ? x2 : c0;  p0.w[2] = hiHalf ? c2 : x0;
        p0.w[1] = hiHalf ? x3 : c1;  p0.w[3] = hiHalf ? c3 : x1;
        p1.w[0] = hiHalf ? x6 : c4;  p1.w[2] = hiHalf ? c6 : x4;
        p1.w[1] = hiHalf ? x7 : c5;  p1.w[3] = hiHalf ? c7 : x5;
#pragma unroll
        for (int dt = 0; dt < 2; ++dt) {
            bf16x8 v0 = *(const bf16x8*)(lds + 16384 + (dt * 16 + st * 2) * 512 + lane * 8);
            bf16x8 v1 = *(const bf16x8*)(lds + 16384 + (dt * 16 + st * 2 + 1) * 512 + lane * 8);
            oacc[dt] = __builtin_amdgcn_mfma_f32_32x32x16_bf16(v0, p0.v, oacc[dt], 0, 0, 0);
            oacc[dt] = __builtin_amdgcn_mfma_f32_32x32x16_bf16(v1, p1.v, oacc[dt], 0, 0, 0);
        }
    }

    // ---- epilogue: normalize, transpose via swizzled LDS (reuse K region), store
    __syncthreads();  // all waves done reading ldsK/ldsV
    u16* ow = lds + wave * 2048;  // 4KB per wave: [q 32][d 64] bf16, XOR-swizzled
    {
        const int q = l31;
#pragma unroll
        for (int dt = 0; dt < 2; ++dt)
#pragma unroll
            for (int rq = 0; rq < 4; ++rq) {
                int d = dt * 32 + rq * 8 + 4 * lh;
                u32 w0 = cvtpk(oacc[dt][rq * 4 + 0] * inv, oacc[dt][rq * 4 + 1] * inv);
                u32 w1 = cvtpk(oacc[dt][rq * 4 + 2] * inv, oacc[dt][rq * 4 + 3] * inv);
                int byte = q * 128 + ((d * 2) ^ ((q & 7) << 4));
                *(u32*)((char*)ow + byte) = w0;
                *(u32*)((char*)ow + byte + 4) = w1;
            }
    }
    __builtin_amdgcn_s_waitcnt(0);  // lgkmcnt drain (same-wave LDS RAW; compiler also guards)
#pragma unroll
    for (int i = 0; i < 4; ++i) {
        int qq = (lane >> 3) + i * 8;
        int byte = qq * 128 + (((lane & 7) * 16) ^ ((qq & 7) << 4));
        bf16x8 val = *(const bf16x8*)((char*)ow + byte);
        *(bf16x8*)(O + (q0 + qq) * 512 + h * 64 + (lane & 7) * 8) = val;
    }
}

// ---------------------------------------------------------------------------
// GroupNorm stats: one block per (b,g); 4096x16 f32 reduction -> per-chan a,d
// ---------------------------------------------------------------------------
__global__ __launch_bounds__(256)
void gn_stats(const float* __restrict__ x, const float* __restrict__ gscale,
              const float* __restrict__ gbias, float* __restrict__ coefA,
              float* __restrict__ coefD)
{
    const int b = blockIdx.x >> 5, g = blockIdx.x & 31;
    const float* base = x + (long)b * 4096 * 512 + g * 16;
    const int tid = threadIdx.x;
    const int p0 = tid >> 2, c0 = (tid & 3) * 4;
    const float* tp = base + (long)p0 * 512 + c0;
    float sum = 0.f, sq = 0.f;
    for (int it = 0; it < 64; ++it) {
        float4 v = *(const float4*)(tp + (long)it * 64 * 512);
        sum += v.x + v.y + v.z + v.w;
        sq += v.x * v.x + v.y * v.y + v.z * v.z + v.w * v.w;
    }
#pragma unroll
    for (int off = 32; off; off >>= 1) {
        sum += __shfl_down(sum, off);
        sq  += __shfl_down(sq, off);
    }
    __shared__ float ssum[4], ssq[4];
    if ((tid & 63) == 0) { ssum[tid >> 6] = sum; ssq[tid >> 6] = sq; }
    __syncthreads();
    if (tid < 16) {
        float S = ssum[0] + ssum[1] + ssum[2] + ssum[3];
        float Q = ssq[0] + ssq[1] + ssq[2] + ssq[3];
        float mean = S * (1.f / 65536.f);
        float var = Q * (1.f / 65536.f) - mean * mean;
        float rstd = rsqrtf(var + 1e-5f);
        int c = g * 16 + tid;
        float a = gscale[c] * rstd;
        coefA[b * 512 + c] = a;
        coefD[b * 512 + c] = gbias[c] - mean * a;
    }
}

// apply GN affine, f32 -> bf16
__global__ __launch_bounds__(256)
void gn_apply(const float* __restrict__ x, const float* __restrict__ coefA,
              const float* __restrict__ coefD, u16* __restrict__ xn)
{
    long e = ((long)blockIdx.x * 256 + threadIdx.x) * 8;
    int b = (int)(e >> 21);
    int c = (int)(e & 511);
    float4 v0 = *(const float4*)(x + e);
    float4 v1 = *(const float4*)(x + e + 4);
    const float* pa = coefA + b * 512 + c;
    const float* pd = coefD + b * 512 + c;
    float f[8] = { v0.x, v0.y, v0.z, v0.w, v1.x, v1.y, v1.z, v1.w };
    u32x4 o;
#pragma unroll
    for (int q = 0; q < 4; ++q) {
        float g0 = f[q * 2] * pa[q * 2] + pd[q * 2];
        float g1 = f[q * 2 + 1] * pa[q * 2 + 1] + pd[q * 2 + 1];
        o[q] = (u32)f2bf(g0) | ((u32)f2bf(g1) << 16);
    }
    *(u32x4*)(xn + e) = o;
}

// f32 -> bf16 bulk convert (n multiple of 8*256)
__global__ __launch_bounds__(256)
void conv_bf16(const float* __restrict__ in, u16* __restrict__ out)
{
    long e = ((long)blockIdx.x * 256 + threadIdx.x) * 8;
    float4 v0 = *(const float4*)(in + e);
    float4 v1 = *(const float4*)(in + e + 4);
    float f[8] = { v0.x, v0.y, v0.z, v0.w, v1.x, v1.y, v1.z, v1.w };
    u32x4 o;
#pragma unroll
    for (int q = 0; q < 4; ++q)
        o[q] = (u32)f2bf(f[q * 2]) | ((u32)f2bf(f[q * 2 + 1]) << 16);
    *(u32x4*)(out + e) = o;
}

// 2D transpose f32 -> bf16 for weights (R,C multiples of 32)
__global__ __launch_bounds__(256)
void transpose_k(const float* __restrict__ in, u16* __restrict__ out, int R, int C)
{
    __shared__ u16 t[32][33];
    int tx = threadIdx.x & 31, ty = threadIdx.x >> 5;
    int r0 = blockIdx.y * 32, c0 = blockIdx.x * 32;
    for (int i = ty; i < 32; i += 8) t[i][tx] = f2bf(in[(long)(r0 + i) * C + c0 + tx]);
    __syncthreads();
    for (int i = ty; i < 32; i += 8) out[(long)(c0 + i) * R + r0 + tx] = t[tx][i];
}

extern "C" void kernel_launch(void* const* d_in, const int* in_sizes, int n_in,
                              void* d_out, int out_size, void* d_ws, size_t ws_size,
                              hipStream_t stream)
{
    const float* x    = (const float*)d_in[0];
    const float* cond = (const float*)d_in[1];
    const float* gsc  = (const float*)d_in[2];
    const float* gbi  = (const float*)d_in[3];
    const float* Wq   = (const float*)d_in[4];
    const float* Wk   = (const float*)d_in[5];
    const float* Wv   = (const float*)d_in[6];
    const float* Wo   = (const float*)d_in[7];
    const float* bo   = (const float*)d_in[8];

    char* ws = (char*)d_ws;
    size_t off = 0;
    auto alloc = [&](size_t bytes) -> void* {
        void* p = ws + off; off += (bytes + 255) & ~(size_t)255; return p;
    };
    u16* WqT   = (u16*)alloc(512 * 512 * 2);
    u16* WkT   = (u16*)alloc(512 * 768 * 2);
    u16* WvT   = (u16*)alloc(512 * 768 * 2);
    u16* WoT   = (u16*)alloc(512 * 512 * 2);
    float* cfA = (float*)alloc(8 * 512 * 4);
    float* cfD = (float*)alloc(8 * 512 * 4);
    u16* condb = (u16*)alloc(2048l * 768 * 2);
    u16* xn    = (u16*)alloc(33554432);   // reused as attention output O
    u16* Qb    = (u16*)alloc(33554432);
    u16* Kb    = (u16*)alloc(2048l * 512 * 2);
    u16* Vt    = (u16*)alloc(2097152);
    u16* Ob = xn;

    transpose_k<<<dim3(16, 16), 256, 0, stream>>>(Wq, WqT, 512, 512);
    transpose_k<<<dim3(16, 24), 256, 0, stream>>>(Wk, WkT, 768, 512);
    transpose_k<<<dim3(16, 24), 256, 0, stream>>>(Wv, WvT, 768, 512);
    transpose_k<<<dim3(16, 16), 256, 0, stream>>>(Wo, WoT, 512, 512);
    conv_bf16<<<768, 256, 0, stream>>>(cond, condb);

    gn_stats<<<256, 256, 0, stream>>>(x, gsc, gbi, cfA, cfD);
    gn_apply<<<8192, 256, 0, stream>>>(x, cfA, cfD, xn);

    // Q = (xn @ WqT) * 0.125  (scale folded; exact in bf16)
    gemm_bt<128, 0, false, false><<<dim3(256, 4, 1), 256, 0, stream>>>(
        xn, WqT, Qb, nullptr, nullptr, 512, 512, 512, 512,
        0, 0, 0, 0, 0, 0, 0.125f);
    // K = cond @ WkT      (2048 x 512 x 768)
    gemm_bt<128, 0, false, false><<<dim3(16, 4, 1), 256, 0, stream>>>(
        condb, WkT, Kb, nullptr, nullptr, 768, 768, 768, 512,
        0, 0, 0, 0, 0, 0, 1.f);
    // V = cond @ WvT, stored transposed per head -> Vt[b*8+h][64][256]
    gemm_bt<128, 2, false, false><<<dim3(16, 4, 1), 256, 0, stream>>>(
        condb, WvT, Vt, nullptr, nullptr, 768, 768, 768, 0,
        0, 0, 0, 0, 0, 0, 1.f);

    // fused attention: scores+softmax+PV, writes Ob
    attn_fused<<<dim3(32, 64), 256, 0, stream>>>(Qb, Kb, Vt, Ob);

    // out = x + O @ WoT + bo    (32768 x 512 x 512), f32 output
    gemm_bt<128, 1, true, true><<<dim3(256, 4, 1), 256, 0, stream>>>(
        Ob, WoT, d_out, bo, x, 512, 512, 512, 512,
        0, 0, 0, 0, 0, 0, 1.f);
}